// Round 11
// baseline (327.744 us; speedup 1.0000x reference)
//
#include <hip/hip_runtime.h>
#include <hip/hip_bf16.h>
#include <math.h>

typedef __attribute__((ext_vector_type(8))) short bf16x8;
typedef __attribute__((ext_vector_type(4))) float f32x4;

__device__ inline short f2bf(float f) {
    __hip_bfloat16 h = __float2bfloat16(f);
    return *reinterpret_cast<short*>(&h);
}

// order-preserving float -> uint map (strictly monotone for non-NaN)
__device__ inline unsigned int obits(float f) {
    unsigned int u = __float_as_uint(f);
    return (u & 0x80000000u) ? ~u : (u | 0x80000000u);
}

// ---------------------------------------------------------------------------
// bf16 MFMA GEMM, 64x64 tile, double-buffered, full-K (bias supported).
// ---------------------------------------------------------------------------
__global__ __launch_bounds__(256) void gemm_mfma64(
    const float* __restrict__ A, long lda, long sAb, long sAh,
    const float* __restrict__ B, long ldb, long sBb, long sBh,
    float* __restrict__ C, long ldc, long sCb, long sCh,
    int K, const float* __restrict__ bias, float scale, int hDiv)
{
    int bz = blockIdx.z;
    int bb = bz / hDiv, hh = bz % hDiv;
    A += bb * sAb + hh * sAh;
    B += bb * sBb + hh * sBh;
    C += bb * sCb + hh * sCh;
    int bm = blockIdx.y * 64, bn = blockIdx.x * 64;

    __shared__ __align__(16) short Asub[2][2048];
    __shared__ __align__(16) short Bsub[2][2048];

    int tid = threadIdx.x;
    int lane = tid & 63;
    int wave = tid >> 6;
    int wr = wave >> 1, wc = wave & 1;
    int l15 = lane & 15, l4 = lane >> 4;

    f32x4 acc[2][2] = {};

    int sr = tid >> 2;
    int sq = tid & 3;
    const float* gA = A + (long)(bm + sr) * lda + sq * 8;
    const float* gB = B + (long)(bn + sr) * ldb + sq * 8;
    int woff = (sr >> 4) * 512 + sq * 128 + (sr & 15) * 8;

    float4 a0 = *(const float4*)(gA);
    float4 a1 = *(const float4*)(gA + 4);
    float4 b0 = *(const float4*)(gB);
    float4 b1 = *(const float4*)(gB + 4);
    {
        bf16x8 ua, ub;
        ua[0]=f2bf(a0.x); ua[1]=f2bf(a0.y); ua[2]=f2bf(a0.z); ua[3]=f2bf(a0.w);
        ua[4]=f2bf(a1.x); ua[5]=f2bf(a1.y); ua[6]=f2bf(a1.z); ua[7]=f2bf(a1.w);
        ub[0]=f2bf(b0.x); ub[1]=f2bf(b0.y); ub[2]=f2bf(b0.z); ub[3]=f2bf(b0.w);
        ub[4]=f2bf(b1.x); ub[5]=f2bf(b1.y); ub[6]=f2bf(b1.z); ub[7]=f2bf(b1.w);
        *(bf16x8*)(Asub[0] + woff) = ua;
        *(bf16x8*)(Bsub[0] + woff) = ub;
    }
    if (K > 32) {
        a0 = *(const float4*)(gA + 32);
        a1 = *(const float4*)(gA + 36);
        b0 = *(const float4*)(gB + 32);
        b1 = *(const float4*)(gB + 36);
    }
    __syncthreads();

    int p = 0;
    for (int k0 = 0; k0 < K; k0 += 32) {
        bf16x8 af[2], bfr[2];
#pragma unroll
        for (int mi = 0; mi < 2; mi++)
            af[mi] = *(const bf16x8*)(Asub[p] + (wr * 2 + mi) * 512 + l4 * 128 + l15 * 8);
#pragma unroll
        for (int ni = 0; ni < 2; ni++)
            bfr[ni] = *(const bf16x8*)(Bsub[p] + (wc * 2 + ni) * 512 + l4 * 128 + l15 * 8);

        if (k0 + 32 < K) {
            bf16x8 ua, ub;
            ua[0]=f2bf(a0.x); ua[1]=f2bf(a0.y); ua[2]=f2bf(a0.z); ua[3]=f2bf(a0.w);
            ua[4]=f2bf(a1.x); ua[5]=f2bf(a1.y); ua[6]=f2bf(a1.z); ua[7]=f2bf(a1.w);
            ub[0]=f2bf(b0.x); ub[1]=f2bf(b0.y); ub[2]=f2bf(b0.z); ub[3]=f2bf(b0.w);
            ub[4]=f2bf(b1.x); ub[5]=f2bf(b1.y); ub[6]=f2bf(b1.z); ub[7]=f2bf(b1.w);
            *(bf16x8*)(Asub[p ^ 1] + woff) = ua;
            *(bf16x8*)(Bsub[p ^ 1] + woff) = ub;
            if (k0 + 64 < K) {
                a0 = *(const float4*)(gA + k0 + 64);
                a1 = *(const float4*)(gA + k0 + 68);
                b0 = *(const float4*)(gB + k0 + 64);
                b1 = *(const float4*)(gB + k0 + 68);
            }
        }

#pragma unroll
        for (int mi = 0; mi < 2; mi++)
#pragma unroll
            for (int ni = 0; ni < 2; ni++)
                acc[mi][ni] = __builtin_amdgcn_mfma_f32_16x16x32_bf16(
                    af[mi], bfr[ni], acc[mi][ni], 0, 0, 0);
        __syncthreads();
        p ^= 1;
    }

#pragma unroll
    for (int ni = 0; ni < 2; ni++) {
        int c = bn + wc * 32 + ni * 16 + l15;
        float bv = bias ? bias[c] : 0.f;
#pragma unroll
        for (int mi = 0; mi < 2; mi++) {
            int r0 = bm + wr * 32 + mi * 16 + l4 * 4;
#pragma unroll
            for (int e = 0; e < 4; e++)
                C[(long)(r0 + e) * ldc + c] = acc[mi][ni][e] * scale + bv;
        }
    }
}

// ---------------------------------------------------------------------------
// Split-K variant: computes K-slice [ks*Ktile, (ks+1)*Ktile), atomicAdds into
// zero-initialized C. z = ks*nbz + bz. No bias.
// ---------------------------------------------------------------------------
__global__ __launch_bounds__(256) void gemm_mfma64_at(
    const float* __restrict__ A, long lda, long sAb, long sAh,
    const float* __restrict__ B, long ldb, long sBb, long sBh,
    float* __restrict__ C, long ldc, long sCb, long sCh,
    int Ktile, float scale, int hDiv, int nbz)
{
    int z = blockIdx.z;
    int bz = z % nbz, ks = z / nbz;
    int bb = bz / hDiv, hh = bz % hDiv;
    A += bb * sAb + hh * sAh + (long)ks * Ktile;
    B += bb * sBb + hh * sBh + (long)ks * Ktile;
    C += bb * sCb + hh * sCh;
    int bm = blockIdx.y * 64, bn = blockIdx.x * 64;

    __shared__ __align__(16) short Asub[2][2048];
    __shared__ __align__(16) short Bsub[2][2048];

    int tid = threadIdx.x;
    int lane = tid & 63;
    int wave = tid >> 6;
    int wr = wave >> 1, wc = wave & 1;
    int l15 = lane & 15, l4 = lane >> 4;

    f32x4 acc[2][2] = {};

    int sr = tid >> 2;
    int sq = tid & 3;
    const float* gA = A + (long)(bm + sr) * lda + sq * 8;
    const float* gB = B + (long)(bn + sr) * ldb + sq * 8;
    int woff = (sr >> 4) * 512 + sq * 128 + (sr & 15) * 8;

    float4 a0 = *(const float4*)(gA);
    float4 a1 = *(const float4*)(gA + 4);
    float4 b0 = *(const float4*)(gB);
    float4 b1 = *(const float4*)(gB + 4);
    {
        bf16x8 ua, ub;
        ua[0]=f2bf(a0.x); ua[1]=f2bf(a0.y); ua[2]=f2bf(a0.z); ua[3]=f2bf(a0.w);
        ua[4]=f2bf(a1.x); ua[5]=f2bf(a1.y); ua[6]=f2bf(a1.z); ua[7]=f2bf(a1.w);
        ub[0]=f2bf(b0.x); ub[1]=f2bf(b0.y); ub[2]=f2bf(b0.z); ub[3]=f2bf(b0.w);
        ub[4]=f2bf(b1.x); ub[5]=f2bf(b1.y); ub[6]=f2bf(b1.z); ub[7]=f2bf(b1.w);
        *(bf16x8*)(Asub[0] + woff) = ua;
        *(bf16x8*)(Bsub[0] + woff) = ub;
    }
    if (Ktile > 32) {
        a0 = *(const float4*)(gA + 32);
        a1 = *(const float4*)(gA + 36);
        b0 = *(const float4*)(gB + 32);
        b1 = *(const float4*)(gB + 36);
    }
    __syncthreads();

    int p = 0;
    for (int k0 = 0; k0 < Ktile; k0 += 32) {
        bf16x8 af[2], bfr[2];
#pragma unroll
        for (int mi = 0; mi < 2; mi++)
            af[mi] = *(const bf16x8*)(Asub[p] + (wr * 2 + mi) * 512 + l4 * 128 + l15 * 8);
#pragma unroll
        for (int ni = 0; ni < 2; ni++)
            bfr[ni] = *(const bf16x8*)(Bsub[p] + (wc * 2 + ni) * 512 + l4 * 128 + l15 * 8);

        if (k0 + 32 < Ktile) {
            bf16x8 ua, ub;
            ua[0]=f2bf(a0.x); ua[1]=f2bf(a0.y); ua[2]=f2bf(a0.z); ua[3]=f2bf(a0.w);
            ua[4]=f2bf(a1.x); ua[5]=f2bf(a1.y); ua[6]=f2bf(a1.z); ua[7]=f2bf(a1.w);
            ub[0]=f2bf(b0.x); ub[1]=f2bf(b0.y); ub[2]=f2bf(b0.z); ub[3]=f2bf(b0.w);
            ub[4]=f2bf(b1.x); ub[5]=f2bf(b1.y); ub[6]=f2bf(b1.z); ub[7]=f2bf(b1.w);
            *(bf16x8*)(Asub[p ^ 1] + woff) = ua;
            *(bf16x8*)(Bsub[p ^ 1] + woff) = ub;
            if (k0 + 64 < Ktile) {
                a0 = *(const float4*)(gA + k0 + 64);
                a1 = *(const float4*)(gA + k0 + 68);
                b0 = *(const float4*)(gB + k0 + 64);
                b1 = *(const float4*)(gB + k0 + 68);
            }
        }

#pragma unroll
        for (int mi = 0; mi < 2; mi++)
#pragma unroll
            for (int ni = 0; ni < 2; ni++)
                acc[mi][ni] = __builtin_amdgcn_mfma_f32_16x16x32_bf16(
                    af[mi], bfr[ni], acc[mi][ni], 0, 0, 0);
        __syncthreads();
        p ^= 1;
    }

#pragma unroll
    for (int ni = 0; ni < 2; ni++) {
        int c = bn + wc * 32 + ni * 16 + l15;
#pragma unroll
        for (int mi = 0; mi < 2; mi++) {
            int r0 = bm + wr * 32 + mi * 16 + l4 * 4;
#pragma unroll
            for (int e = 0; e < 4; e++)
                atomicAdd(&C[(long)(r0 + e) * ldc + c], acc[mi][ni][e] * scale);
        }
    }
}

// ---------------------------------------------------------------------------
// fp32 q-projection, 32x64 tile (512 blocks -> 2/CU TLP), fused bias+BN.
// ---------------------------------------------------------------------------
__global__ __launch_bounds__(256) void sgemm_qproj(
    const float* __restrict__ A, const float* __restrict__ W,
    float* __restrict__ Q,
    const float* __restrict__ bq, const float* __restrict__ bn_w,
    const float* __restrict__ bn_b, const float* __restrict__ bn_mean,
    const float* __restrict__ bn_var)
{
    int bm = blockIdx.y * 32, bn = blockIdx.x * 64;
    __shared__ float As[32][34];   // [k][row], padded
    __shared__ float Bs[32][64];   // [k][col]
    int tid = threadIdx.x;
    int tx = tid & 15, ty = tid >> 4;
    int ar = tid >> 3, ak = (tid & 7) * 4;    // A stage
    int br = tid & 63, bk = (tid >> 6) * 8;   // B stage
    float acc[2][4] = {{0.f}};

    const float* ga = A + (long)(bm + ar) * 1024 + ak;
    const float* gb = W + (long)(bn + br) * 1024 + bk;

    float4 a0 = *(const float4*)(ga);
    float4 b0 = *(const float4*)(gb);
    float4 b1 = *(const float4*)(gb + 4);

    for (int k0 = 0; k0 < 1024; k0 += 32) {
        __syncthreads();
        As[ak + 0][ar] = a0.x; As[ak + 1][ar] = a0.y;
        As[ak + 2][ar] = a0.z; As[ak + 3][ar] = a0.w;
        Bs[bk + 0][br] = b0.x; Bs[bk + 1][br] = b0.y;
        Bs[bk + 2][br] = b0.z; Bs[bk + 3][br] = b0.w;
        Bs[bk + 4][br] = b1.x; Bs[bk + 5][br] = b1.y;
        Bs[bk + 6][br] = b1.z; Bs[bk + 7][br] = b1.w;
        if (k0 + 32 < 1024) {
            a0 = *(const float4*)(ga + k0 + 32);
            b0 = *(const float4*)(gb + k0 + 32);
            b1 = *(const float4*)(gb + k0 + 36);
        }
        __syncthreads();
#pragma unroll
        for (int kk = 0; kk < 32; kk++) {
            float2 av = *(const float2*)&As[kk][ty * 2];
            float4 bv = *(const float4*)&Bs[kk][tx * 4];
            float a[2] = {av.x, av.y};
            float b[4] = {bv.x, bv.y, bv.z, bv.w};
#pragma unroll
            for (int i = 0; i < 2; i++)
#pragma unroll
                for (int j = 0; j < 4; j++)
                    acc[i][j] = fmaf(a[i], b[j], acc[i][j]);
        }
    }

#pragma unroll
    for (int j = 0; j < 4; j++) {
        int n = bn + tx * 4 + j;
        float s = rsqrtf(bn_var[n] + 1e-5f) * bn_w[n];
        float base = bq[n] - bn_mean[n];
        float bb = bn_b[n];
#pragma unroll
        for (int i = 0; i < 2; i++) {
            long m = bm + ty * 2 + i;
            Q[m * 1024 + n] = (acc[i][j] + base) * s + bb;
        }
    }
}

// ---------------------------------------------------------------------------
// va^T: vat[z][n][k] = va[b][k][h*128+n], z=b*8+h
// ---------------------------------------------------------------------------
__global__ __launch_bounds__(256) void transpose_va(
    const float* __restrict__ qkv, float* __restrict__ vat)
{
    int z = blockIdx.z;
    int b = z >> 3, h = z & 7;
    int k0 = blockIdx.x * 32, n0 = blockIdx.y * 32;
    __shared__ float tile[32][33];
    int tx = threadIdx.x & 31, ty = threadIdx.x >> 5;
    const float* src = qkv + 2048 + (long)b * 1572864 + (long)h * 128;
#pragma unroll
    for (int i = 0; i < 4; i++)
        tile[ty + 8 * i][tx] = src[(long)(k0 + ty + 8 * i) * 3072 + n0 + tx];
    __syncthreads();
    float* dst = vat + (long)z * 65536;
#pragma unroll
    for (int i = 0; i < 4; i++)
        dst[(long)(n0 + ty + 8 * i) * 512 + k0 + tx] = tile[tx][ty + 8 * i];
}

// ---------------------------------------------------------------------------
// Fused PEER v6: u64 keys + ulonglong2 LDS reads everywhere in ranking.
// ---------------------------------------------------------------------------
__global__ __launch_bounds__(128) void peer_kernel(
    const float* __restrict__ q,        // (8192,128)
    const float* __restrict__ sub_keys, // (2,128,64)
    const float* __restrict__ ew,       // (16384,128)
    float* __restrict__ out)            // (8192,128)
{
    int th = blockIdx.x;
    int tid = threadIdx.x;

    __shared__ __align__(16) float qrow[128];
    __shared__ __align__(16) unsigned long long k1s[128];
    __shared__ __align__(16) unsigned long long k2s[128];
    __shared__ __align__(16) unsigned long long cks[256];
    __shared__ float tv1[16], tv2[16];
    __shared__ int   ti1[16], ti2[16];
    __shared__ int   part[100];
    __shared__ int   eid[16];
    __shared__ float simv[16];
    __shared__ float rw[16];

    qrow[tid] = q[(long)th * 128 + tid];
    __syncthreads();

    // A: sub-key scores (float4 qrow reads)
    float a1 = 0.f, a2 = 0.f;
    {
        const float4* k1 = (const float4*)(sub_keys + tid * 64);
        const float4* k2 = (const float4*)(sub_keys + 8192 + tid * 64);
#pragma unroll 4
        for (int c = 0; c < 16; c++) {
            float4 q1 = *(const float4*)&qrow[4 * c];
            float4 q2 = *(const float4*)&qrow[64 + 4 * c];
            float4 v1 = k1[c], v2 = k2[c];
            a1 = fmaf(q1.x, v1.x, a1); a1 = fmaf(q1.y, v1.y, a1);
            a1 = fmaf(q1.z, v1.z, a1); a1 = fmaf(q1.w, v1.w, a1);
            a2 = fmaf(q2.x, v2.x, a2); a2 = fmaf(q2.y, v2.y, a2);
            a2 = fmaf(q2.z, v2.z, a2); a2 = fmaf(q2.w, v2.w, a2);
        }
    }
    unsigned long long key1 = ((unsigned long long)obits(a1) << 32) | (unsigned)(127 - tid);
    unsigned long long key2 = ((unsigned long long)obits(a2) << 32) | (unsigned)(127 - tid);
    k1s[tid] = key1;
    k2s[tid] = key2;
    __syncthreads();

    // B: rank via u64 compares, b128 reads (2 keys/read)
    {
        int r1 = 0, r2 = 0;
#pragma unroll 8
        for (int j = 0; j < 128; j += 2) {
            ulonglong2 ka = *(const ulonglong2*)&k1s[j];
            ulonglong2 kb = *(const ulonglong2*)&k2s[j];
            r1 += (ka.x > key1) + (ka.y > key1);
            r2 += (kb.x > key2) + (kb.y > key2);
        }
        if (r1 < 16) { tv1[r1] = a1; ti1[r1] = tid; }
        if (r2 < 16) { tv2[r2] = a2; ti2[r2] = tid; }
    }
    __syncthreads();

    // C1: 256 candidate u64 keys (sum desc, ties -> lower expert id)
    {
        int c0 = tid, c1 = tid + 128;
        float s0 = tv1[c0 >> 4] + tv2[c0 & 15];
        int e0 = ti1[c0 >> 4] * 128 + ti2[c0 & 15];
        cks[c0] = ((unsigned long long)obits(s0) << 32) | (unsigned)(16383 - e0);
        float s1v = tv1[c1 >> 4] + tv2[c1 & 15];
        int e1 = ti1[c1 >> 4] * 128 + ti2[c1 & 15];
        cks[c1] = ((unsigned long long)obits(s1v) << 32) | (unsigned)(16383 - e1);
    }
    __syncthreads();

    // C2: rank staircase candidates {(i,j):(i+1)(j+1)<=16} vs all 256
    if (tid < 100) {
        int c = tid >> 1, h = tid & 1;
        int i, j;
        if      (c < 16) { i = 0; j = c; }
        else if (c < 24) { i = 1; j = c - 16; }
        else if (c < 29) { i = 2; j = c - 24; }
        else if (c < 33) { i = 3; j = c - 29; }
        else if (c < 36) { i = 4; j = c - 33; }
        else if (c < 38) { i = 5; j = c - 36; }
        else if (c < 40) { i = 6; j = c - 38; }
        else if (c < 42) { i = 7; j = c - 40; }
        else             { i = 8 + (c - 42); j = 0; }
        unsigned long long mk = cks[i * 16 + j];
        const ulonglong2* base = (const ulonglong2*)(cks + h * 128);
        int cnt = 0;
#pragma unroll 8
        for (int t = 0; t < 64; t++) {
            ulonglong2 kk = base[t];
            cnt += (kk.x > mk);
            cnt += (kk.y > mk);
        }
        part[tid] = cnt;
    }
    __syncthreads();
    if (tid < 50) {
        int r = part[2 * tid] + part[2 * tid + 1];
        if (r < 16) {
            int c = tid;
            int i, j;
            if      (c < 16) { i = 0; j = c; }
            else if (c < 24) { i = 1; j = c - 16; }
            else if (c < 29) { i = 2; j = c - 24; }
            else if (c < 33) { i = 3; j = c - 29; }
            else if (c < 36) { i = 4; j = c - 33; }
            else if (c < 38) { i = 5; j = c - 36; }
            else if (c < 40) { i = 6; j = c - 38; }
            else if (c < 42) { i = 7; j = c - 40; }
            else             { i = 8 + (c - 42); j = 0; }
            eid[r] = ti1[i] * 128 + ti2[j];
        }
    }
    __syncthreads();

    // D: sim via 8 threads per expert + shuffle reduce
    {
        int e = tid >> 3, g = tid & 7;
        const float4* e4 = (const float4*)(ew + (long)eid[e] * 128 + g * 16);
        const float4* qb = (const float4*)(qrow + g * 16);
        float acc = 0.f;
#pragma unroll
        for (int m = 0; m < 4; m++) {
            float4 v = e4[m];
            float4 qv = qb[m];
            acc = fmaf(qv.x, v.x, acc);
            acc = fmaf(qv.y, v.y, acc);
            acc = fmaf(qv.z, v.z, acc);
            acc = fmaf(qv.w, v.w, acc);
        }
        acc += __shfl_down(acc, 4);
        acc += __shfl_down(acc, 2);
        acc += __shfl_down(acc, 1);
        if (g == 0) simv[e] = acc;
    }
    __syncthreads();

    if (tid < 16) {
        float mx = simv[0];
#pragma unroll
        for (int k = 1; k < 16; k++) mx = fmaxf(mx, simv[k]);
        rw[tid] = expf(simv[tid] - mx);
    }
    __syncthreads();

    {
        float wsum = 0.f;
#pragma unroll
        for (int k = 0; k < 16; k++) wsum += rw[k];
        float inv = 1.f / wsum;
        float o = 0.f;
#pragma unroll
        for (int k = 0; k < 16; k++)
            o = fmaf(rw[k], ew[(long)eid[k] * 128 + tid], o);
        out[(long)th * 128 + tid] = o * inv;
    }
}

// ---------------------------------------------------------------------------
// Fused attention softmax + head-mean.
// ---------------------------------------------------------------------------
__global__ __launch_bounds__(256) void softmax_mean(
    float* __restrict__ att, float* __restrict__ outw)
{
    int blk = blockIdx.x;
    int b = blk >> 9, row = blk & 511;
    int tid = threadIdx.x;
    int w = tid >> 6, lane = tid & 63;

    __shared__ float msum[4][516];

#pragma unroll
    for (int pass = 0; pass < 2; pass++) {
        int h = w + pass * 4;
        long base = ((long)(b * 8 + h) * 512 + row) * 512 + lane * 8;
        float4 v0 = *(const float4*)(att + base);
        float4 v1 = *(const float4*)(att + base + 4);
        float m = fmaxf(fmaxf(fmaxf(v0.x, v0.y), fmaxf(v0.z, v0.w)),
                        fmaxf(fmaxf(v1.x, v1.y), fmaxf(v1.z, v1.w)));
#pragma unroll
        for (int off = 32; off > 0; off >>= 1)
            m = fmaxf(m, __shfl_xor(m, off));
        float e[8];
        e[0] = expf(v0.x - m); e[1] = expf(v0.y - m);
        e[2] = expf(v0.z - m); e[3] = expf(v0.w - m);
        e[4] = expf(v1.x - m); e[5] = expf(v1.y - m);
        e[6] = expf(v1.z - m); e[7] = expf(v1.w - m);
        float s = e[0] + e[1] + e[2] + e[3] + e[4] + e[5] + e[6] + e[7];
#pragma unroll
        for (int off = 32; off > 0; off >>= 1)
            s += __shfl_xor(s, off);
        float inv = 1.f / s;
        float4 p0 = make_float4(e[0] * inv, e[1] * inv, e[2] * inv, e[3] * inv);
        float4 p1 = make_float4(e[4] * inv, e[5] * inv, e[6] * inv, e[7] * inv);
        *(float4*)(att + base) = p0;
        *(float4*)(att + base + 4) = p1;
        int c = lane * 8;
        if (pass == 0) {
            msum[w][c + 0] = p0.x; msum[w][c + 1] = p0.y;
            msum[w][c + 2] = p0.z; msum[w][c + 3] = p0.w;
            msum[w][c + 4] = p1.x; msum[w][c + 5] = p1.y;
            msum[w][c + 6] = p1.z; msum[w][c + 7] = p1.w;
        } else {
            msum[w][c + 0] += p0.x; msum[w][c + 1] += p0.y;
            msum[w][c + 2] += p0.z; msum[w][c + 3] += p0.w;
            msum[w][c + 4] += p1.x; msum[w][c + 5] += p1.y;
            msum[w][c + 6] += p1.z; msum[w][c + 7] += p1.w;
        }
    }
    __syncthreads();
#pragma unroll
    for (int i = 0; i < 2; i++) {
        int c = tid + i * 256;
        float s = (msum[0][c] + msum[1][c] + msum[2][c] + msum[3][c]) * 0.125f;
        outw[(long)blk * 512 + c] = s;
    }
}

// ---------------------------------------------------------------------------
// y = rmsnorm(x + out2 + ao2 + bo + attn_ob) * rms_w   (biases folded here)
// ---------------------------------------------------------------------------
__global__ __launch_bounds__(256) void final_fuse(
    const float* __restrict__ x, const float* __restrict__ out2,
    const float* __restrict__ ao2, const float* __restrict__ rms_w,
    const float* __restrict__ bo, const float* __restrict__ attn_ob,
    float* __restrict__ y)
{
    long base = (long)blockIdx.x * 1024;
    int tid = threadIdx.x;
    float v[4];
    float ss = 0.f;
#pragma unroll
    for (int i = 0; i < 4; i++) {
        int d = tid + i * 256;
        v[i] = x[base + d] + out2[base + d] + ao2[base + d] + bo[d] + attn_ob[d];
        ss = fmaf(v[i], v[i], ss);
    }
    __shared__ float red[256];
    red[tid] = ss;
    __syncthreads();
    for (int st = 128; st > 0; st >>= 1) {
        if (tid < st) red[tid] += red[tid + st];
        __syncthreads();
    }
    float scale = rsqrtf(red[0] * (1.f / 1024.f) + 1e-6f);
#pragma unroll
    for (int i = 0; i < 4; i++) {
        int d = tid + i * 256;
        y[base + d] = v[i] * scale * rms_w[d];
    }
}

// ---------------------------------------------------------------------------
extern "C" void kernel_launch(void* const* d_in, const int* in_sizes, int n_in,
                              void* d_out, int out_size, void* d_ws, size_t ws_size,
                              hipStream_t stream)
{
    const float* x         = (const float*)d_in[0];
    const float* wq        = (const float*)d_in[1];
    const float* bq        = (const float*)d_in[2];
    const float* bn_w      = (const float*)d_in[3];
    const float* bn_b      = (const float*)d_in[4];
    const float* bn_mean   = (const float*)d_in[5];
    const float* bn_var    = (const float*)d_in[6];
    const float* sub_keys  = (const float*)d_in[7];
    const float* ew        = (const float*)d_in[8];
    const float* wo        = (const float*)d_in[9];
    const float* bo        = (const float*)d_in[10];
    const float* in_proj_w = (const float*)d_in[11];
    const float* in_proj_b = (const float*)d_in[12];
    const float* attn_ow   = (const float*)d_in[13];
    const float* attn_ob   = (const float*)d_in[14];
    const float* rms_w     = (const float*)d_in[15];
    float* out = (float*)d_out;

    float* ws   = (float*)d_ws;
    float* q    = ws;                 // 1024x1024 (dead after peer; reused as vat)
    float* peer = ws + 1048576;       // 1024x1024
    float* out2 = ws + 2097152;       // 1024x1024
    float* qkv  = ws + 3145728;       // 1024x3072
    float* att  = ws + 6291456;       // 16x512x512
    float* ao   = ws + 10485760;      // 1024x1024
    float* ao2  = ws + 11534336;      // 1024x1024
    float* vat  = q;                  // 16x128x512 (aliases q)

    dim3 blk(256);

    // zero split-K accumulation buffers (ws is poisoned 0xAA each launch)
    hipMemsetAsync(out2, 0, 4194304, stream);
    hipMemsetAsync(ao,   0, 4194304, stream);
    hipMemsetAsync(ao2,  0, 4194304, stream);

    // 1. q = BN(x @ wq^T + bq)   (fp32 exact, 512 blocks)
    sgemm_qproj<<<dim3(16, 32, 1), blk, 0, stream>>>(
        x, wq, q, bq, bn_w, bn_b, bn_mean, bn_var);

    // 2. PEER
    peer_kernel<<<8192, 128, 0, stream>>>(q, sub_keys, ew, peer);

    // 3. out2 += peer @ wo^T   (split-K 4 -> 1024 blocks; bo in final_fuse)
    gemm_mfma64_at<<<dim3(16, 16, 4), blk, 0, stream>>>(
        peer, 1024L, 0L, 0L, wo, 1024L, 0L, 0L, out2, 1024L, 0L, 0L,
        256, 1.0f, 1, 1);

    // 4. qkv = x @ in_proj^T + b   (768 blocks)
    gemm_mfma64<<<dim3(48, 16, 1), blk, 0, stream>>>(
        x, 1024L, 0L, 0L, in_proj_w, 1024L, 0L, 0L, qkv, 3072L, 0L, 0L,
        1024, in_proj_b, 1.0f, 1);

    // 5. vat = va^T
    transpose_va<<<dim3(16, 4, 16), blk, 0, stream>>>(qkv, vat);

    // 6. att scores = qa @ ka^T / sqrt(128)   (1024 blocks)
    gemm_mfma64<<<dim3(8, 8, 16), blk, 0, stream>>>(
        qkv, 3072L, 1572864L, 128L,
        qkv + 1024, 3072L, 1572864L, 128L,
        att, 512L, 2097152L, 262144L,
        128, nullptr, 0.08838834764831845f, 8);

    // 7. softmax + head-mean; mean -> out[1048576:]
    softmax_mean<<<1024, 256, 0, stream>>>(att, out + 1048576);

    // 8. ao += att @ vat^T   (split-K 2 -> 512 blocks)
    gemm_mfma64_at<<<dim3(2, 8, 32), blk, 0, stream>>>(
        att, 512L, 2097152L, 262144L,
        vat, 512L, 524288L, 65536L,
        ao, 1024L, 524288L, 128L,
        256, 1.0f, 8, 16);

    // 9. ao2 += ao @ attn_ow^T   (split-K 4 -> 1024 blocks; bias in final_fuse)
    gemm_mfma64_at<<<dim3(16, 16, 4), blk, 0, stream>>>(
        ao, 1024L, 0L, 0L, attn_ow, 1024L, 0L, 0L, ao2, 1024L, 0L, 0L,
        256, 1.0f, 1, 1);

    // 10. final fuse -> out[0:1048576]
    final_fuse<<<1024, 256, 0, stream>>>(x, out2, ao2, rms_w, bo, attn_ob, out);
}